// Round 22
// baseline (110.114 us; speedup 1.0000x reference)
//
#include <hip/hip_runtime.h>

#define NN 100000
#define NE 1200000
#define FF 64
#define NBIN 512
#define BIN_NODES 196 // 512*196 = 100352 >= 100000
#define BINCAP 2752   // per-bin edge capacity (even): mean 2352 + ~8 sigma
#define LSTR 9        // LDS row stride in uint4 (144B) -> conflict-free b128 r/w

using bf16x8 = __attribute__((ext_vector_type(8))) short;
using f32x4  = __attribute__((ext_vector_type(4))) float;

__device__ __forceinline__ unsigned short f2bf(float x) {   // RNE bf16
    unsigned u = __float_as_uint(x);
    unsigned r = u + 0x7fffu + ((u >> 16) & 1u);
    return (unsigned short)(r >> 16);
}
__device__ __forceinline__ unsigned pack_bf2(float lo, float hi) {
    return (unsigned)f2bf(lo) | ((unsigned)f2bf(hi) << 16);
}
__device__ __forceinline__ float bf2f_lo(unsigned v) {
    return __uint_as_float(v << 16);
}
__device__ __forceinline__ float bf2f_hi(unsigned v) {
    return __uint_as_float(v & 0xffff0000u);
}

// ---------------- prep: zero gptr + convert W0/W1 to fragment-order bf16 ------
__global__ __launch_bounds__(512) void prep_w(
        const float* __restrict__ W0, const float* __restrict__ W1,
        unsigned short* __restrict__ W0b, unsigned short* __restrict__ W1b,
        int* gptr) {
    int t = threadIdx.x;            // 512 threads: q = t>>4, l16 = t&15
    gptr[t] = 0;
    int q = t >> 4, l16 = t & 15;
    int ct = q >> 3, kh = (q >> 2) & 1, lg = q & 3;
    int col = ct * 16 + l16;
#pragma unroll
    for (int j = 0; j < 8; ++j) {
        int k = kh * 32 + lg * 8 + j;
        W0b[(size_t)t * 8 + j] = f2bf(W0[k * FF + col]);
        W1b[(size_t)t * 8 + j] = f2bf(W1[k * FF + col]);
    }
}

// ---------------- phase 1: bin edges by dst range ----------------
__global__ __launch_bounds__(1024) void bin_edges(
        const int* __restrict__ esrc, const int* __restrict__ edst,
        const float* __restrict__ ew, int* gptr, int2* __restrict__ binbuf, int e) {
    __shared__ int lcnt[NBIN];
    __shared__ int lbase[NBIN];
    int tid = threadIdx.x;
    int per = (e + (int)gridDim.x - 1) / (int)gridDim.x;
    int lo = blockIdx.x * per;
    int hi = min(lo + per, e);

    if (tid < NBIN) lcnt[tid] = 0;
    __syncthreads();

    for (int i = lo + tid; i < hi; i += 1024) {
        int b = (int)((unsigned)edst[i] / BIN_NODES);
        atomicAdd(&lcnt[b], 1);
    }
    __syncthreads();

    if (tid < NBIN) {
        int c = lcnt[tid];
        lbase[tid] = (c > 0) ? atomicAdd(&gptr[tid], c) : 0;
        lcnt[tid] = 0;
    }
    __syncthreads();

    for (int i = lo + tid; i < hi; i += 1024) {
        int d = edst[i];
        int b = (int)((unsigned)d / BIN_NODES);
        int s = atomicAdd(&lcnt[b], 1);
        int pos = lbase[b] + s;
        if (pos < BINCAP)
            binbuf[(size_t)b * BINCAP + pos] =
                make_int2(esrc[i] | ((d - b * BIN_NODES) << 17),
                          __float_as_int(ew[i]));
    }
}

// ---------------- phase 2: compact CSR build + dinv + t0 ----------------
__global__ __launch_bounds__(512) void build_compact(
        const int* __restrict__ gptr, const int2* __restrict__ binbuf,
        const float* __restrict__ x, int2* __restrict__ bucket,
        int* __restrict__ meta, float* __restrict__ dinv,
        uint4* __restrict__ t0, int n) {
    __shared__ int2  lbuck[BINCAP];        // 22 KB
    __shared__ int   lc[BIN_NODES];
    __shared__ int   loff[BIN_NODES];
    __shared__ float ldeg[BIN_NODES];
    __shared__ int   sc[256];
    int b = blockIdx.x, tid = threadIdx.x;

    for (int i = tid; i < BIN_NODES; i += 512) { lc[i] = 0; ldeg[i] = 0.0f; }
    __syncthreads();

    int ce = min(gptr[b], BINCAP);
    const int2* bb = binbuf + (size_t)b * BINCAP;

    for (int i = tid; i < ce; i += 512) {
        int2 r = bb[i];
        int ln = (unsigned)r.x >> 17;
        atomicAdd(&lc[ln], 1);
        atomicAdd(&ldeg[ln], __int_as_float(r.y));
    }
    __syncthreads();

    if (tid < 256) sc[tid] = (tid < BIN_NODES) ? ((lc[tid] + 1) & ~1) : 0;
    __syncthreads();
#pragma unroll
    for (int s = 1; s < 256; s <<= 1) {
        int v = (tid < 256 && tid >= s) ? sc[tid - s] : 0;
        __syncthreads();
        if (tid < 256) sc[tid] += v;
        __syncthreads();
    }
    if (tid < BIN_NODES) loff[tid] = sc[tid] - ((lc[tid] + 1) & ~1);
    __syncthreads();
    int total = sc[BIN_NODES - 1];

    for (int i = tid; i < total; i += 512) lbuck[i] = make_int2(0, 0);
    __syncthreads();
    if (tid < BIN_NODES) lc[tid] = loff[tid];
    __syncthreads();

    for (int i = tid; i < ce; i += 512) {
        int2 r = bb[i];
        int ln = (unsigned)r.x >> 17;
        int pos = atomicAdd(&lc[ln], 1);
        lbuck[pos] = make_int2(r.x & 0x1FFFF, r.y);
    }
    __syncthreads();

    int gbase = b * BIN_NODES;
    for (int i = tid; i < BIN_NODES; i += 512) {
        float di = rsqrtf(ldeg[i] + 1.0f);   // + self loop
        int g = gbase + i;
        if (g < n) {
            dinv[g] = di;
            meta[g] = loff[i] | ((sc[i] - loff[i]) << 16);
        }
        ldeg[i] = di;
    }
    __syncthreads();

    {
        int lim4 = total >> 1;
        const int4* s4 = (const int4*)lbuck;
        int4* d4 = (int4*)(bucket + (size_t)b * BINCAP);
        for (int i = tid; i < lim4; i += 512) d4[i] = s4[i];
    }

    int eg = tid >> 3, l = tid & 7;
    for (int i = eg; i < BIN_NODES; i += 64) {
        int g = gbase + i;
        if (g >= n) continue;
        float di = ldeg[i];
        const float4* xp = (const float4*)(x + (size_t)g * FF + l * 8);
        float4 v0 = xp[0], v1 = xp[1];
        uint4 o;
        o.x = pack_bf2(v0.x * di, v0.y * di);
        o.y = pack_bf2(v0.z * di, v0.w * di);
        o.z = pack_bf2(v1.x * di, v1.y * di);
        o.w = pack_bf2(v1.z * di, v1.w * di);
        t0[(size_t)g * 8 + l] = o;
    }
}

// ---------------- agg helper: 8 edges in flight, FMA into 8 lanes -------------
#define EDGE_FMA(q, vv) do { \
    float w_ = __int_as_float(q); \
    a0 = fmaf(w_, bf2f_lo((vv).x), a0); a1 = fmaf(w_, bf2f_hi((vv).x), a1); \
    a2 = fmaf(w_, bf2f_lo((vv).y), a2); a3 = fmaf(w_, bf2f_hi((vv).y), a3); \
    a4 = fmaf(w_, bf2f_lo((vv).z), a4); a5 = fmaf(w_, bf2f_hi((vv).z), a5); \
    a6 = fmaf(w_, bf2f_lo((vv).w), a6); a7 = fmaf(w_, bf2f_hi((vv).w), a7); \
} while (0)

__device__ __forceinline__ void agg_node(
        const int* __restrict__ meta, const int4* __restrict__ bucket4,
        const uint4* __restrict__ t, const float* __restrict__ dinv,
        int node, int l, uint4* __restrict__ ldsrow) {
    uint4 sv = t[(size_t)node * 8 + l];
    float a0 = bf2f_lo(sv.x), a1 = bf2f_hi(sv.x);
    float a2 = bf2f_lo(sv.y), a3 = bf2f_hi(sv.y);
    float a4 = bf2f_lo(sv.z), a5 = bf2f_hi(sv.z);
    float a6 = bf2f_lo(sv.w), a7 = bf2f_hi(sv.w);

    int m = meta[node];
    int c = m >> 16;                      // even
    int bin = (int)((unsigned)node / BIN_NODES);
    const int4* bp = bucket4 + (((size_t)bin * BINCAP + (m & 0xFFFF)) >> 1);
    int p = 0;
    for (; p + 7 < c; p += 8) {          // 8 edges in flight
        int4 q0 = bp[(p >> 1) + 0];
        int4 q1 = bp[(p >> 1) + 1];
        int4 q2 = bp[(p >> 1) + 2];
        int4 q3 = bp[(p >> 1) + 3];
        uint4 v0 = t[q0.x * 8 + l];
        uint4 v1 = t[q0.z * 8 + l];
        uint4 v2 = t[q1.x * 8 + l];
        uint4 v3 = t[q1.z * 8 + l];
        uint4 v4 = t[q2.x * 8 + l];
        uint4 v5 = t[q2.z * 8 + l];
        uint4 v6 = t[q3.x * 8 + l];
        uint4 v7 = t[q3.z * 8 + l];
        EDGE_FMA(q0.y, v0); EDGE_FMA(q0.w, v1);
        EDGE_FMA(q1.y, v2); EDGE_FMA(q1.w, v3);
        EDGE_FMA(q2.y, v4); EDGE_FMA(q2.w, v5);
        EDGE_FMA(q3.y, v6); EDGE_FMA(q3.w, v7);
    }
    if (p + 3 < c) {                     // one 4-edge step
        int4 q0 = bp[(p >> 1) + 0];
        int4 q1 = bp[(p >> 1) + 1];
        uint4 v0 = t[q0.x * 8 + l];
        uint4 v1 = t[q0.z * 8 + l];
        uint4 v2 = t[q1.x * 8 + l];
        uint4 v3 = t[q1.z * 8 + l];
        EDGE_FMA(q0.y, v0); EDGE_FMA(q0.w, v1);
        EDGE_FMA(q1.y, v2); EDGE_FMA(q1.w, v3);
        p += 4;
    }
    if (p < c) {                         // one 2-edge step (c even)
        int4 q0 = bp[p >> 1];
        uint4 v0 = t[q0.x * 8 + l];
        uint4 v1 = t[q0.z * 8 + l];
        EDGE_FMA(q0.y, v0); EDGE_FMA(q0.w, v1);
    }
    float di = dinv[node];
    uint4 o;
    o.x = pack_bf2(a0 * di, a1 * di);
    o.y = pack_bf2(a2 * di, a3 * di);
    o.z = pack_bf2(a4 * di, a5 * di);
    o.w = pack_bf2(a6 * di, a7 * di);
    ldsrow[l] = o;
}

// ---------------- fused layer 0: agg(32 nodes) -> LDS -> MFMA -> t1 -----------
__global__ __launch_bounds__(256) void fused_aggA(
        const int* __restrict__ meta, const int4* __restrict__ bucket4,
        const uint4* __restrict__ t, const float* __restrict__ dinv,
        const bf16x8* __restrict__ Wb, const float* __restrict__ b,
        unsigned short* __restrict__ t1) {
    __shared__ uint4 lds[32 * LSTR];   // 4.6 KB, 144B row stride
    int tid = threadIdx.x;
    int r = tid >> 3, l = tid & 7;
    int nodebase = blockIdx.x * 32;
    agg_node(meta, bucket4, t, dinv, nodebase + r, l, &lds[r * LSTR]);
    __syncthreads();

    int wid = tid >> 6, lane = tid & 63;
    if (wid >= 2) return;
    int l16 = lane & 15, lg = lane >> 4;
    int rloc = wid * 16 + l16;
    int rowbase = nodebase + wid * 16;

    bf16x8 a0 = *(const bf16x8*)&lds[rloc * LSTR + lg];
    bf16x8 a1 = *(const bf16x8*)&lds[rloc * LSTR + lg + 4];

#pragma unroll
    for (int ct = 0; ct < 4; ++ct) {
        bf16x8 bf0 = Wb[((ct * 2 + 0) * 4 + lg) * 16 + l16];
        bf16x8 bf1 = Wb[((ct * 2 + 1) * 4 + lg) * 16 + l16];
        f32x4 acc = (f32x4){0.f, 0.f, 0.f, 0.f};
        acc = __builtin_amdgcn_mfma_f32_16x16x32_bf16(a0, bf0, acc, 0, 0, 0);
        acc = __builtin_amdgcn_mfma_f32_16x16x32_bf16(a1, bf1, acc, 0, 0, 0);
        float bias_ = b[ct * 16 + l16];
#pragma unroll
        for (int rr = 0; rr < 4; ++rr) {
            int row = rowbase + lg * 4 + rr;
            float h = fmaxf(acc[rr] + bias_, 0.0f) * dinv[row];
            t1[(size_t)row * FF + ct * 16 + l16] = f2bf(h);
        }
    }
}

// ---------------- fused layer 1: agg -> LDS -> MFMA -> relu -> .W2 -> t3 ------
__global__ __launch_bounds__(256) void fused_aggB(
        const int* __restrict__ meta, const int4* __restrict__ bucket4,
        const uint4* __restrict__ t, const float* __restrict__ dinv,
        const bf16x8* __restrict__ Wb, const float* __restrict__ b1,
        const float* __restrict__ W2, float* __restrict__ t3) {
    __shared__ uint4 lds[32 * LSTR];
    int tid = threadIdx.x;
    int r = tid >> 3, l = tid & 7;
    int nodebase = blockIdx.x * 32;
    agg_node(meta, bucket4, t, dinv, nodebase + r, l, &lds[r * LSTR]);
    __syncthreads();

    int wid = tid >> 6, lane = tid & 63;
    if (wid >= 2) return;
    int l16 = lane & 15, lg = lane >> 4;
    int rloc = wid * 16 + l16;
    int rowbase = nodebase + wid * 16;

    bf16x8 a0 = *(const bf16x8*)&lds[rloc * LSTR + lg];
    bf16x8 a1 = *(const bf16x8*)&lds[rloc * LSTR + lg + 4];

    float pr[4] = {0.f, 0.f, 0.f, 0.f};
#pragma unroll
    for (int ct = 0; ct < 4; ++ct) {
        bf16x8 bf0 = Wb[((ct * 2 + 0) * 4 + lg) * 16 + l16];
        bf16x8 bf1 = Wb[((ct * 2 + 1) * 4 + lg) * 16 + l16];
        f32x4 acc = (f32x4){0.f, 0.f, 0.f, 0.f};
        acc = __builtin_amdgcn_mfma_f32_16x16x32_bf16(a0, bf0, acc, 0, 0, 0);
        acc = __builtin_amdgcn_mfma_f32_16x16x32_bf16(a1, bf1, acc, 0, 0, 0);
        float bias_ = b1[ct * 16 + l16];
        float w2_ = W2[ct * 16 + l16];
#pragma unroll
        for (int rr = 0; rr < 4; ++rr)
            pr[rr] = fmaf(fmaxf(acc[rr] + bias_, 0.0f), w2_, pr[rr]);
    }
#pragma unroll
    for (int rr = 0; rr < 4; ++rr) {
        pr[rr] += __shfl_xor(pr[rr], 1, 64);
        pr[rr] += __shfl_xor(pr[rr], 2, 64);
        pr[rr] += __shfl_xor(pr[rr], 4, 64);
        pr[rr] += __shfl_xor(pr[rr], 8, 64);
    }
    if (l16 == 0) {
#pragma unroll
        for (int rr = 0; rr < 4; ++rr) {
            int row = rowbase + lg * 4 + rr;
            t3[row] = pr[rr] * dinv[row];
        }
    }
}

// ---------------- final: out = dinv*(sum w*t3[src] + t3[d]) + b2 --------------
__global__ __launch_bounds__(256) void final_out(
        const int* __restrict__ meta, const int2* __restrict__ bucket,
        const float* __restrict__ t3, const float* __restrict__ dinv,
        const float* __restrict__ b2, float* __restrict__ out, int n) {
    int node = blockIdx.x * 16 + (threadIdx.x >> 4);
    int l = threadIdx.x & 15;
    if (node >= n) return;
    int m = meta[node];
    int c = m >> 16;
    int bin = (int)((unsigned)node / BIN_NODES);
    const int2* bp = bucket + (size_t)bin * BINCAP + (m & 0xFFFF);
    float v = 0.0f;
    for (int p = l; p < c; p += 16) {
        int2 ed = bp[p];
        v = fmaf(__int_as_float(ed.y), t3[ed.x], v);   // dummy: w=0
    }
    v += __shfl_xor(v, 1, 64);
    v += __shfl_xor(v, 2, 64);
    v += __shfl_xor(v, 4, 64);
    v += __shfl_xor(v, 8, 64);
    if (l == 0) out[node] = (v + t3[node]) * dinv[node] + b2[0];
}

// ---------------- launch ----------------
extern "C" void kernel_launch(void* const* d_in, const int* in_sizes, int n_in,
                              void* d_out, int out_size, void* d_ws, size_t ws_size,
                              hipStream_t stream) {
    const float* x  = (const float*)d_in[0];
    const int* esrc = (const int*)d_in[1];
    const int* edst = (const int*)d_in[2];
    const float* ew = (const float*)d_in[3];
    const float* W0 = (const float*)d_in[4];
    const float* b0 = (const float*)d_in[5];
    const float* W1 = (const float*)d_in[6];
    const float* b1 = (const float*)d_in[7];
    const float* W2 = (const float*)d_in[8];
    const float* b2 = (const float*)d_in[9];
    float* out = (float*)d_out;

    const int n = NN, e = NE;

    char* ws = (char*)d_ws;
    size_t off = 0;
    auto alloc = [&](size_t bytes) {
        char* p = ws + off;
        off += (bytes + 255) & ~size_t(255);
        return p;
    };
    int*   meta   = (int*)  alloc(size_t(n) * 4);
    float* dinv   = (float*)alloc(size_t(n) * 4);
    float* t3     = (float*)alloc(size_t(n) * 4);
    int*   gptr   = (int*)  alloc(size_t(NBIN) * 4);
    unsigned short* W0b = (unsigned short*)alloc(4096 * 2);   // 8 KB
    unsigned short* W1b = (unsigned short*)alloc(4096 * 2);
    int2*  bucket = (int2*) alloc(size_t(NBIN) * BINCAP * 8);      // 11.3 MB compact
    unsigned short* zbuf = (unsigned short*)alloc(size_t(n) * FF * 2); // 12.8 MB
    unsigned short* t0   = (unsigned short*)alloc(size_t(n) * FF * 2); // 12.8 MB
    (void)ws_size;

    int2* binbuf = (int2*)zbuf;      // dead after build_compact
    unsigned short* t1 = zbuf;       // fused_aggA writes t1 here

    int gFuse = n / 32;              // 3125, exact
    int gFin  = (n + 15) / 16;       // 6250

    prep_w<<<1, 512, 0, stream>>>(W0, W1, W0b, W1b, gptr);
    bin_edges<<<256, 1024, 0, stream>>>(esrc, edst, ew, gptr, binbuf, e);
    build_compact<<<NBIN, 512, 0, stream>>>(gptr, binbuf, x, bucket, meta, dinv,
                                            (uint4*)t0, n);
    fused_aggA<<<gFuse, 256, 0, stream>>>(meta, (const int4*)bucket,
                                          (const uint4*)t0, dinv,
                                          (const bf16x8*)W0b, b0, t1);
    fused_aggB<<<gFuse, 256, 0, stream>>>(meta, (const int4*)bucket,
                                          (const uint4*)t1, dinv,
                                          (const bf16x8*)W1b, b1, W2, t3);
    final_out<<<gFin, 256, 0, stream>>>(meta, (const int2*)bucket, t3, dinv, b2, out, n);
}

// Round 23
// 107.656 us; speedup vs baseline: 1.0228x; 1.0228x over previous
//
#include <hip/hip_runtime.h>

#define NN 100000
#define NE 1200000
#define FF 64
#define NBIN 512
#define BIN_NODES 196 // 512*196 = 100352 >= 100000
#define BINCAP 2752   // per-bin edge capacity (even): mean 2352 + ~8 sigma
#define LSTR 9        // LDS row stride in uint4 (144B) -> conflict-free b128 r/w

using bf16x8 = __attribute__((ext_vector_type(8))) short;
using f32x4  = __attribute__((ext_vector_type(4))) float;

__device__ __forceinline__ unsigned short f2bf(float x) {   // RNE bf16
    unsigned u = __float_as_uint(x);
    unsigned r = u + 0x7fffu + ((u >> 16) & 1u);
    return (unsigned short)(r >> 16);
}
__device__ __forceinline__ unsigned pack_bf2(float lo, float hi) {
    return (unsigned)f2bf(lo) | ((unsigned)f2bf(hi) << 16);
}
__device__ __forceinline__ float bf2f_lo(unsigned v) {
    return __uint_as_float(v << 16);
}
__device__ __forceinline__ float bf2f_hi(unsigned v) {
    return __uint_as_float(v & 0xffff0000u);
}

// ---------------- prep: zero gptr + convert W0/W1 to fragment-order bf16 ------
// Wb layout: chunk index q = (ct*2+kh)*4+lg in [0,32); within chunk, 16 lanes
// (l16) each own 8 contiguous bf16 = W[(kh*32+lg*8+j)*FF + ct*16+l16], j=0..7.
__global__ __launch_bounds__(512) void prep_w(
        const float* __restrict__ W0, const float* __restrict__ W1,
        unsigned short* __restrict__ W0b, unsigned short* __restrict__ W1b,
        int* gptr) {
    int t = threadIdx.x;            // 512 threads: q = t>>4, l16 = t&15
    gptr[t] = 0;
    int q = t >> 4, l16 = t & 15;
    int ct = q >> 3, kh = (q >> 2) & 1, lg = q & 3;
    int col = ct * 16 + l16;
#pragma unroll
    for (int j = 0; j < 8; ++j) {
        int k = kh * 32 + lg * 8 + j;
        W0b[(size_t)t * 8 + j] = f2bf(W0[k * FF + col]);
        W1b[(size_t)t * 8 + j] = f2bf(W1[k * FF + col]);
    }
}

// ---------------- phase 1: bin edges by dst range ----------------
__global__ __launch_bounds__(1024) void bin_edges(
        const int* __restrict__ esrc, const int* __restrict__ edst,
        const float* __restrict__ ew, int* gptr, int2* __restrict__ binbuf, int e) {
    __shared__ int lcnt[NBIN];
    __shared__ int lbase[NBIN];
    int tid = threadIdx.x;
    int per = (e + (int)gridDim.x - 1) / (int)gridDim.x;
    int lo = blockIdx.x * per;
    int hi = min(lo + per, e);

    if (tid < NBIN) lcnt[tid] = 0;
    __syncthreads();

    for (int i = lo + tid; i < hi; i += 1024) {
        int b = (int)((unsigned)edst[i] / BIN_NODES);
        atomicAdd(&lcnt[b], 1);
    }
    __syncthreads();

    if (tid < NBIN) {
        int c = lcnt[tid];
        lbase[tid] = (c > 0) ? atomicAdd(&gptr[tid], c) : 0;
        lcnt[tid] = 0;
    }
    __syncthreads();

    for (int i = lo + tid; i < hi; i += 1024) {
        int d = edst[i];
        int b = (int)((unsigned)d / BIN_NODES);
        int s = atomicAdd(&lcnt[b], 1);
        int pos = lbase[b] + s;
        if (pos < BINCAP)
            binbuf[(size_t)b * BINCAP + pos] =
                make_int2(esrc[i] | ((d - b * BIN_NODES) << 17),
                          __float_as_int(ew[i]));
    }
}

// ---------------- phase 2: compact CSR build + dinv + t0 ----------------
__global__ __launch_bounds__(512) void build_compact(
        const int* __restrict__ gptr, const int2* __restrict__ binbuf,
        const float* __restrict__ x, int2* __restrict__ bucket,
        int* __restrict__ meta, float* __restrict__ dinv,
        uint4* __restrict__ t0, int n) {
    __shared__ int2  lbuck[BINCAP];        // 22 KB
    __shared__ int   lc[BIN_NODES];
    __shared__ int   loff[BIN_NODES];
    __shared__ float ldeg[BIN_NODES];
    __shared__ int   sc[256];
    int b = blockIdx.x, tid = threadIdx.x;

    for (int i = tid; i < BIN_NODES; i += 512) { lc[i] = 0; ldeg[i] = 0.0f; }
    __syncthreads();

    int ce = min(gptr[b], BINCAP);
    const int2* bb = binbuf + (size_t)b * BINCAP;

    for (int i = tid; i < ce; i += 512) {
        int2 r = bb[i];
        int ln = (unsigned)r.x >> 17;
        atomicAdd(&lc[ln], 1);
        atomicAdd(&ldeg[ln], __int_as_float(r.y));
    }
    __syncthreads();

    if (tid < 256) sc[tid] = (tid < BIN_NODES) ? ((lc[tid] + 1) & ~1) : 0;
    __syncthreads();
#pragma unroll
    for (int s = 1; s < 256; s <<= 1) {
        int v = (tid < 256 && tid >= s) ? sc[tid - s] : 0;
        __syncthreads();
        if (tid < 256) sc[tid] += v;
        __syncthreads();
    }
    if (tid < BIN_NODES) loff[tid] = sc[tid] - ((lc[tid] + 1) & ~1);
    __syncthreads();
    int total = sc[BIN_NODES - 1];

    for (int i = tid; i < total; i += 512) lbuck[i] = make_int2(0, 0);
    __syncthreads();
    if (tid < BIN_NODES) lc[tid] = loff[tid];
    __syncthreads();

    for (int i = tid; i < ce; i += 512) {
        int2 r = bb[i];
        int ln = (unsigned)r.x >> 17;
        int pos = atomicAdd(&lc[ln], 1);
        lbuck[pos] = make_int2(r.x & 0x1FFFF, r.y);
    }
    __syncthreads();

    int gbase = b * BIN_NODES;
    for (int i = tid; i < BIN_NODES; i += 512) {
        float di = rsqrtf(ldeg[i] + 1.0f);   // + self loop
        int g = gbase + i;
        if (g < n) {
            dinv[g] = di;
            meta[g] = loff[i] | ((sc[i] - loff[i]) << 16);
        }
        ldeg[i] = di;
    }
    __syncthreads();

    {
        int lim4 = total >> 1;
        const int4* s4 = (const int4*)lbuck;
        int4* d4 = (int4*)(bucket + (size_t)b * BINCAP);
        for (int i = tid; i < lim4; i += 512) d4[i] = s4[i];
    }

    int eg = tid >> 3, l = tid & 7;
    for (int i = eg; i < BIN_NODES; i += 64) {
        int g = gbase + i;
        if (g >= n) continue;
        float di = ldeg[i];
        const float4* xp = (const float4*)(x + (size_t)g * FF + l * 8);
        float4 v0 = xp[0], v1 = xp[1];
        uint4 o;
        o.x = pack_bf2(v0.x * di, v0.y * di);
        o.y = pack_bf2(v0.z * di, v0.w * di);
        o.z = pack_bf2(v1.x * di, v1.y * di);
        o.w = pack_bf2(v1.z * di, v1.w * di);
        t0[(size_t)g * 8 + l] = o;
    }
}

// ---------------- agg helper: z-row (8 bf16 feats of one node) into LDS -------
__device__ __forceinline__ void agg_node(
        const int* __restrict__ meta, const int4* __restrict__ bucket4,
        const uint4* __restrict__ t, const float* __restrict__ dinv,
        int node, int l, uint4* __restrict__ ldsrow) {
    uint4 sv = t[(size_t)node * 8 + l];
    float a0 = bf2f_lo(sv.x), a1 = bf2f_hi(sv.x);
    float a2 = bf2f_lo(sv.y), a3 = bf2f_hi(sv.y);
    float a4 = bf2f_lo(sv.z), a5 = bf2f_hi(sv.z);
    float a6 = bf2f_lo(sv.w), a7 = bf2f_hi(sv.w);

    int m = meta[node];
    int c = m >> 16;                      // even
    int bin = (int)((unsigned)node / BIN_NODES);
    const int4* bp = bucket4 + (((size_t)bin * BINCAP + (m & 0xFFFF)) >> 1);
    int p = 0;
    for (; p + 3 < c; p += 4) {
        int4 q0 = bp[(p >> 1) + 0];
        int4 q1 = bp[(p >> 1) + 1];
        uint4 v0 = t[q0.x * 8 + l];
        uint4 v1 = t[q0.z * 8 + l];
        uint4 v2 = t[q1.x * 8 + l];
        uint4 v3 = t[q1.z * 8 + l];
        float w0 = __int_as_float(q0.y), w1 = __int_as_float(q0.w);
        float w2 = __int_as_float(q1.y), w3 = __int_as_float(q1.w);
        a0 = fmaf(w0, bf2f_lo(v0.x), a0); a1 = fmaf(w0, bf2f_hi(v0.x), a1);
        a2 = fmaf(w0, bf2f_lo(v0.y), a2); a3 = fmaf(w0, bf2f_hi(v0.y), a3);
        a4 = fmaf(w0, bf2f_lo(v0.z), a4); a5 = fmaf(w0, bf2f_hi(v0.z), a5);
        a6 = fmaf(w0, bf2f_lo(v0.w), a6); a7 = fmaf(w0, bf2f_hi(v0.w), a7);
        a0 = fmaf(w1, bf2f_lo(v1.x), a0); a1 = fmaf(w1, bf2f_hi(v1.x), a1);
        a2 = fmaf(w1, bf2f_lo(v1.y), a2); a3 = fmaf(w1, bf2f_hi(v1.y), a3);
        a4 = fmaf(w1, bf2f_lo(v1.z), a4); a5 = fmaf(w1, bf2f_hi(v1.z), a5);
        a6 = fmaf(w1, bf2f_lo(v1.w), a6); a7 = fmaf(w1, bf2f_hi(v1.w), a7);
        a0 = fmaf(w2, bf2f_lo(v2.x), a0); a1 = fmaf(w2, bf2f_hi(v2.x), a1);
        a2 = fmaf(w2, bf2f_lo(v2.y), a2); a3 = fmaf(w2, bf2f_hi(v2.y), a3);
        a4 = fmaf(w2, bf2f_lo(v2.z), a4); a5 = fmaf(w2, bf2f_hi(v2.z), a5);
        a6 = fmaf(w2, bf2f_lo(v2.w), a6); a7 = fmaf(w2, bf2f_hi(v2.w), a7);
        a0 = fmaf(w3, bf2f_lo(v3.x), a0); a1 = fmaf(w3, bf2f_hi(v3.x), a1);
        a2 = fmaf(w3, bf2f_lo(v3.y), a2); a3 = fmaf(w3, bf2f_hi(v3.y), a3);
        a4 = fmaf(w3, bf2f_lo(v3.z), a4); a5 = fmaf(w3, bf2f_hi(v3.z), a5);
        a6 = fmaf(w3, bf2f_lo(v3.w), a6); a7 = fmaf(w3, bf2f_hi(v3.w), a7);
    }
    if (p < c) {
        int4 q0 = bp[p >> 1];
        uint4 v0 = t[q0.x * 8 + l];
        uint4 v1 = t[q0.z * 8 + l];
        float w0 = __int_as_float(q0.y), w1 = __int_as_float(q0.w);
        a0 = fmaf(w0, bf2f_lo(v0.x), a0); a1 = fmaf(w0, bf2f_hi(v0.x), a1);
        a2 = fmaf(w0, bf2f_lo(v0.y), a2); a3 = fmaf(w0, bf2f_hi(v0.y), a3);
        a4 = fmaf(w0, bf2f_lo(v0.z), a4); a5 = fmaf(w0, bf2f_hi(v0.z), a5);
        a6 = fmaf(w0, bf2f_lo(v0.w), a6); a7 = fmaf(w0, bf2f_hi(v0.w), a7);
        a0 = fmaf(w1, bf2f_lo(v1.x), a0); a1 = fmaf(w1, bf2f_hi(v1.x), a1);
        a2 = fmaf(w1, bf2f_lo(v1.y), a2); a3 = fmaf(w1, bf2f_hi(v1.y), a3);
        a4 = fmaf(w1, bf2f_lo(v1.z), a4); a5 = fmaf(w1, bf2f_hi(v1.z), a5);
        a6 = fmaf(w1, bf2f_lo(v1.w), a6); a7 = fmaf(w1, bf2f_hi(v1.w), a7);
    }
    float di = dinv[node];
    uint4 o;
    o.x = pack_bf2(a0 * di, a1 * di);
    o.y = pack_bf2(a2 * di, a3 * di);
    o.z = pack_bf2(a4 * di, a5 * di);
    o.w = pack_bf2(a6 * di, a7 * di);
    ldsrow[l] = o;
}

// ---------------- fused layer 0: agg(32 nodes) -> LDS -> MFMA -> t1 -----------
__global__ __launch_bounds__(256) void fused_aggA(
        const int* __restrict__ meta, const int4* __restrict__ bucket4,
        const uint4* __restrict__ t, const float* __restrict__ dinv,
        const bf16x8* __restrict__ Wb, const float* __restrict__ b,
        unsigned short* __restrict__ t1) {
    __shared__ uint4 lds[32 * LSTR];   // 4.6 KB, 144B row stride
    int tid = threadIdx.x;
    int r = tid >> 3, l = tid & 7;
    int nodebase = blockIdx.x * 32;
    agg_node(meta, bucket4, t, dinv, nodebase + r, l, &lds[r * LSTR]);
    __syncthreads();

    int wid = tid >> 6, lane = tid & 63;
    if (wid >= 2) return;
    int l16 = lane & 15, lg = lane >> 4;
    int rloc = wid * 16 + l16;
    int rowbase = nodebase + wid * 16;

    bf16x8 a0 = *(const bf16x8*)&lds[rloc * LSTR + lg];
    bf16x8 a1 = *(const bf16x8*)&lds[rloc * LSTR + lg + 4];

#pragma unroll
    for (int ct = 0; ct < 4; ++ct) {
        bf16x8 bf0 = Wb[((ct * 2 + 0) * 4 + lg) * 16 + l16];
        bf16x8 bf1 = Wb[((ct * 2 + 1) * 4 + lg) * 16 + l16];
        f32x4 acc = (f32x4){0.f, 0.f, 0.f, 0.f};
        acc = __builtin_amdgcn_mfma_f32_16x16x32_bf16(a0, bf0, acc, 0, 0, 0);
        acc = __builtin_amdgcn_mfma_f32_16x16x32_bf16(a1, bf1, acc, 0, 0, 0);
        float bias_ = b[ct * 16 + l16];
#pragma unroll
        for (int rr = 0; rr < 4; ++rr) {
            int row = rowbase + lg * 4 + rr;
            float h = fmaxf(acc[rr] + bias_, 0.0f) * dinv[row];
            t1[(size_t)row * FF + ct * 16 + l16] = f2bf(h);
        }
    }
}

// ---------------- fused layer 1: agg -> LDS -> MFMA -> relu -> .W2 -> t3 ------
__global__ __launch_bounds__(256) void fused_aggB(
        const int* __restrict__ meta, const int4* __restrict__ bucket4,
        const uint4* __restrict__ t, const float* __restrict__ dinv,
        const bf16x8* __restrict__ Wb, const float* __restrict__ b1,
        const float* __restrict__ W2, float* __restrict__ t3) {
    __shared__ uint4 lds[32 * LSTR];
    int tid = threadIdx.x;
    int r = tid >> 3, l = tid & 7;
    int nodebase = blockIdx.x * 32;
    agg_node(meta, bucket4, t, dinv, nodebase + r, l, &lds[r * LSTR]);
    __syncthreads();

    int wid = tid >> 6, lane = tid & 63;
    if (wid >= 2) return;
    int l16 = lane & 15, lg = lane >> 4;
    int rloc = wid * 16 + l16;
    int rowbase = nodebase + wid * 16;

    bf16x8 a0 = *(const bf16x8*)&lds[rloc * LSTR + lg];
    bf16x8 a1 = *(const bf16x8*)&lds[rloc * LSTR + lg + 4];

    float pr[4] = {0.f, 0.f, 0.f, 0.f};
#pragma unroll
    for (int ct = 0; ct < 4; ++ct) {
        bf16x8 bf0 = Wb[((ct * 2 + 0) * 4 + lg) * 16 + l16];
        bf16x8 bf1 = Wb[((ct * 2 + 1) * 4 + lg) * 16 + l16];
        f32x4 acc = (f32x4){0.f, 0.f, 0.f, 0.f};
        acc = __builtin_amdgcn_mfma_f32_16x16x32_bf16(a0, bf0, acc, 0, 0, 0);
        acc = __builtin_amdgcn_mfma_f32_16x16x32_bf16(a1, bf1, acc, 0, 0, 0);
        float bias_ = b1[ct * 16 + l16];
        float w2_ = W2[ct * 16 + l16];
#pragma unroll
        for (int rr = 0; rr < 4; ++rr)
            pr[rr] = fmaf(fmaxf(acc[rr] + bias_, 0.0f), w2_, pr[rr]);
    }
#pragma unroll
    for (int rr = 0; rr < 4; ++rr) {
        pr[rr] += __shfl_xor(pr[rr], 1, 64);
        pr[rr] += __shfl_xor(pr[rr], 2, 64);
        pr[rr] += __shfl_xor(pr[rr], 4, 64);
        pr[rr] += __shfl_xor(pr[rr], 8, 64);
    }
    if (l16 == 0) {
#pragma unroll
        for (int rr = 0; rr < 4; ++rr) {
            int row = rowbase + lg * 4 + rr;
            t3[row] = pr[rr] * dinv[row];
        }
    }
}

// ---------------- final: out = dinv*(sum w*t3[src] + t3[d]) + b2 --------------
// 16-lane groups: 4 nodes per wave, 16 nodes per block.
__global__ __launch_bounds__(256) void final_out(
        const int* __restrict__ meta, const int2* __restrict__ bucket,
        const float* __restrict__ t3, const float* __restrict__ dinv,
        const float* __restrict__ b2, float* __restrict__ out, int n) {
    int node = blockIdx.x * 16 + (threadIdx.x >> 4);
    int l = threadIdx.x & 15;
    if (node >= n) return;
    int m = meta[node];
    int c = m >> 16;
    int bin = (int)((unsigned)node / BIN_NODES);
    const int2* bp = bucket + (size_t)bin * BINCAP + (m & 0xFFFF);
    float v = 0.0f;
    for (int p = l; p < c; p += 16) {
        int2 ed = bp[p];
        v = fmaf(__int_as_float(ed.y), t3[ed.x], v);   // dummy: w=0
    }
    v += __shfl_xor(v, 1, 64);
    v += __shfl_xor(v, 2, 64);
    v += __shfl_xor(v, 4, 64);
    v += __shfl_xor(v, 8, 64);
    if (l == 0) out[node] = (v + t3[node]) * dinv[node] + b2[0];
}

// ---------------- launch ----------------
extern "C" void kernel_launch(void* const* d_in, const int* in_sizes, int n_in,
                              void* d_out, int out_size, void* d_ws, size_t ws_size,
                              hipStream_t stream) {
    const float* x  = (const float*)d_in[0];
    const int* esrc = (const int*)d_in[1];
    const int* edst = (const int*)d_in[2];
    const float* ew = (const float*)d_in[3];
    const float* W0 = (const float*)d_in[4];
    const float* b0 = (const float*)d_in[5];
    const float* W1 = (const float*)d_in[6];
    const float* b1 = (const float*)d_in[7];
    const float* W2 = (const float*)d_in[8];
    const float* b2 = (const float*)d_in[9];
    float* out = (float*)d_out;

    const int n = NN, e = NE;

    char* ws = (char*)d_ws;
    size_t off = 0;
    auto alloc = [&](size_t bytes) {
        char* p = ws + off;
        off += (bytes + 255) & ~size_t(255);
        return p;
    };
    int*   meta   = (int*)  alloc(size_t(n) * 4);
    float* dinv   = (float*)alloc(size_t(n) * 4);
    float* t3     = (float*)alloc(size_t(n) * 4);
    int*   gptr   = (int*)  alloc(size_t(NBIN) * 4);
    unsigned short* W0b = (unsigned short*)alloc(4096 * 2);   // 8 KB
    unsigned short* W1b = (unsigned short*)alloc(4096 * 2);
    int2*  bucket = (int2*) alloc(size_t(NBIN) * BINCAP * 8);      // 11.3 MB compact
    unsigned short* zbuf = (unsigned short*)alloc(size_t(n) * FF * 2); // 12.8 MB
    unsigned short* t0   = (unsigned short*)alloc(size_t(n) * FF * 2); // 12.8 MB
    (void)ws_size;

    int2* binbuf = (int2*)zbuf;      // dead after build_compact
    unsigned short* t1 = zbuf;       // fused_aggA writes t1 here

    int gFuse = n / 32;              // 3125, exact
    int gFin  = (n + 15) / 16;       // 6250

    prep_w<<<1, 512, 0, stream>>>(W0, W1, W0b, W1b, gptr);
    bin_edges<<<256, 1024, 0, stream>>>(esrc, edst, ew, gptr, binbuf, e);
    build_compact<<<NBIN, 512, 0, stream>>>(gptr, binbuf, x, bucket, meta, dinv,
                                            (uint4*)t0, n);
    fused_aggA<<<gFuse, 256, 0, stream>>>(meta, (const int4*)bucket,
                                          (const uint4*)t0, dinv,
                                          (const bf16x8*)W0b, b0, t1);
    fused_aggB<<<gFuse, 256, 0, stream>>>(meta, (const int4*)bucket,
                                          (const uint4*)t1, dinv,
                                          (const bf16x8*)W1b, b1, W2, t3);
    final_out<<<gFin, 256, 0, stream>>>(meta, (const int2*)bucket, t3, dinv, b2, out, n);
}